// Round 1
// baseline (19820.218 us; speedup 1.0000x reference)
//
#include <hip/hip_runtime.h>
#include <hip/hip_bf16.h>

#define HD   1024
#define GD   4096   // 4*H
#define TT   4096
#define NWG  256

// ---------------------------------------------------------------- embed
__global__ void embed_kernel(const int* __restrict__ tokens,
                             const float* __restrict__ emb,
                             float* __restrict__ X) {
    int t = blockIdx.x;
    int tok = tokens[t];
    const float4* src = reinterpret_cast<const float4*>(emb + (size_t)tok * HD);
    float4* dst = reinterpret_cast<float4*>(X + (size_t)t * HD);
    dst[threadIdx.x] = src[threadIdx.x];
}

// ---------------------------------------------------------------- gx GEMM
// gx[t][n] = sum_k X[t][k] * Wih[n][k] + bih[n] + bhh[n]
#define BM 128
#define BN 128
#define BK 16
#define LDP 132   // padded leading dim (16B-aligned rows, bank-spread)

__global__ __launch_bounds__(256, 2) void gemm_gx(
    const float* __restrict__ X,      // TT x HD
    const float* __restrict__ Wih,    // GD x HD
    const float* __restrict__ bih,
    const float* __restrict__ bhh,
    float* __restrict__ gxout)        // TT x GD
{
    __shared__ float As[BK][LDP];
    __shared__ float Bs[BK][LDP];
    const int tid = threadIdx.x;
    const int m0 = blockIdx.x * BM;
    const int n0 = blockIdx.y * BN;
    const int tx = tid & 15;
    const int ty = tid >> 4;

    float acc[8][8] = {};

    for (int kt = 0; kt < HD; kt += BK) {
#pragma unroll
        for (int p = 0; p < 2; ++p) {
            int e = p * 256 + tid;           // 0..511 float4 slots
            int row = e >> 2;
            int quad = e & 3;
            float4 av = *reinterpret_cast<const float4*>(
                &X[(size_t)(m0 + row) * HD + kt + quad * 4]);
            float4 bv = *reinterpret_cast<const float4*>(
                &Wih[(size_t)(n0 + row) * HD + kt + quad * 4]);
            As[quad * 4 + 0][row] = av.x;
            As[quad * 4 + 1][row] = av.y;
            As[quad * 4 + 2][row] = av.z;
            As[quad * 4 + 3][row] = av.w;
            Bs[quad * 4 + 0][row] = bv.x;
            Bs[quad * 4 + 1][row] = bv.y;
            Bs[quad * 4 + 2][row] = bv.z;
            Bs[quad * 4 + 3][row] = bv.w;
        }
        __syncthreads();
#pragma unroll
        for (int k = 0; k < BK; ++k) {
            float4 a0 = *reinterpret_cast<const float4*>(&As[k][ty * 8]);
            float4 a1 = *reinterpret_cast<const float4*>(&As[k][ty * 8 + 4]);
            float4 b0 = *reinterpret_cast<const float4*>(&Bs[k][tx * 8]);
            float4 b1 = *reinterpret_cast<const float4*>(&Bs[k][tx * 8 + 4]);
            float a[8] = {a0.x, a0.y, a0.z, a0.w, a1.x, a1.y, a1.z, a1.w};
            float b[8] = {b0.x, b0.y, b0.z, b0.w, b1.x, b1.y, b1.z, b1.w};
#pragma unroll
            for (int i = 0; i < 8; ++i)
#pragma unroll
                for (int j = 0; j < 8; ++j)
                    acc[i][j] += a[i] * b[j];
        }
        __syncthreads();
    }

    float bias[8];
#pragma unroll
    for (int j = 0; j < 8; ++j) {
        int n = n0 + tx * 8 + j;
        bias[j] = bih[n] + bhh[n];
    }
#pragma unroll
    for (int i = 0; i < 8; ++i) {
        size_t o = (size_t)(m0 + ty * 8 + i) * GD + n0 + tx * 8;
        float4 s0 = {acc[i][0] + bias[0], acc[i][1] + bias[1],
                     acc[i][2] + bias[2], acc[i][3] + bias[3]};
        float4 s1 = {acc[i][4] + bias[4], acc[i][5] + bias[5],
                     acc[i][6] + bias[6], acc[i][7] + bias[7]};
        *reinterpret_cast<float4*>(&gxout[o]) = s0;
        *reinterpret_cast<float4*>(&gxout[o + 4]) = s1;
    }
}

// ---------------------------------------------------------------- LSTM scan
// 256 WGs x 256 threads. WG b owns h elements j = 4b..4b+3 (16 gate rows).
// Weights live in VGPRs (64 f32/thread). h broadcast via tagged 64-bit
// mailbox words in global memory (ping-pong by step parity).
__global__ __launch_bounds__(256, 1) void lstm_scan(
    const float* __restrict__ gx,                 // TT x GD (includes biases)
    const float* __restrict__ whh,                // GD x HD
    float* __restrict__ out,                      // TT*HD + HD + HD
    unsigned long long* __restrict__ hbuf)        // 2 x HD
{
    const int tid = threadIdx.x;
    const int b = blockIdx.x;
    const int chunk = tid & 15;          // 16 col-chunks of 64
    const int row_local = tid >> 4;      // 0..15
    const int gate = row_local >> 2;
    const int jj = row_local & 3;
    const int R = gate * HD + b * 4 + jj;

    // weights -> registers
    float w[64];
    {
        const float4* wp = reinterpret_cast<const float4*>(
            whh + (size_t)R * HD + chunk * 64);
#pragma unroll
        for (int q = 0; q < 16; ++q) {
            float4 v = wp[q];
            w[q * 4 + 0] = v.x; w[q * 4 + 1] = v.y;
            w[q * 4 + 2] = v.z; w[q * 4 + 3] = v.w;
        }
    }

    __shared__ float h_lds[HD];
    __shared__ float gsum[16];

#pragma unroll
    for (int q = 0; q < 4; ++q) h_lds[tid * 4 + q] = 0.f;   // h(0) = 0
    __syncthreads();

    const bool leader = (tid < 4);
    const int j_out = b * 4 + tid;       // valid for leaders
    float c_reg = 0.f;

    float gxi = 0.f, gxf = 0.f, gxg = 0.f, gxo = 0.f;
    if (leader) {
        const float* gr = gx;            // row 0 (step 1)
        gxi = gr[j_out];
        gxf = gr[HD + j_out];
        gxg = gr[2 * HD + j_out];
        gxo = gr[3 * HD + j_out];
    }

    for (int step = 1; step <= TT; ++step) {
        // prefetch next step's gx early (hides HBM latency under the step)
        float ni = 0.f, nf = 0.f, ng = 0.f, no = 0.f;
        if (leader && step < TT) {
            const float* gr = gx + (size_t)step * GD;
            ni = gr[j_out];
            nf = gr[HD + j_out];
            ng = gr[2 * HD + j_out];
            no = gr[3 * HD + j_out];
        }

        // 16 dot products (length 1024) across the WG
        float acc = 0.f;
        {
            const float4* hb4 = reinterpret_cast<const float4*>(&h_lds[chunk * 64]);
#pragma unroll
            for (int q = 0; q < 16; ++q) {
                float4 hv = hb4[q];
                acc += w[q * 4 + 0] * hv.x;
                acc += w[q * 4 + 1] * hv.y;
                acc += w[q * 4 + 2] * hv.z;
                acc += w[q * 4 + 3] * hv.w;
            }
        }
        acc += __shfl_xor(acc, 1, 64);
        acc += __shfl_xor(acc, 2, 64);
        acc += __shfl_xor(acc, 4, 64);
        acc += __shfl_xor(acc, 8, 64);
        if (chunk == 0) gsum[row_local] = acc;
        __syncthreads();

        if (leader) {
            float xi = gsum[0 * 4 + tid] + gxi;
            float xf = gsum[1 * 4 + tid] + gxf;
            float xg = gsum[2 * 4 + tid] + gxg;
            float xo = gsum[3 * 4 + tid] + gxo;
            float ii = 1.f / (1.f + __expf(-xi));
            float ff = 1.f / (1.f + __expf(-xf));
            float gg = tanhf(xg);
            float oo = 1.f / (1.f + __expf(-xo));
            c_reg = ff * c_reg + ii * gg;
            float hh = oo * tanhf(c_reg);

            // publish FIRST (critical path for all other WGs)
            unsigned long long pkt =
                ((unsigned long long)(unsigned)step << 32) | __float_as_uint(hh);
            __hip_atomic_store(&hbuf[(step & 1) * HD + j_out], pkt,
                               __ATOMIC_RELAXED, __HIP_MEMORY_SCOPE_AGENT);
            h_lds[j_out] = hh;                          // own slice via LDS
            out[(size_t)(step - 1) * HD + j_out] = hh;  // hs output
            if (step == TT) {
                out[(size_t)TT * HD + j_out] = hh;              // h_n
                out[(size_t)TT * HD + HD + j_out] = c_reg;      // c_n
            }
            gxi = ni; gxf = nf; gxg = ng; gxo = no;
        }

        // fetch h(step): thread t owns WG t's 4 words; skip own WG (LDS path)
        if (step < TT) {
            if (tid != b) {
                unsigned long long* src = &hbuf[(step & 1) * HD + tid * 4];
                unsigned long long v0 = 0, v1 = 0, v2 = 0, v3 = 0;
                bool k0 = false, k1 = false, k2 = false, k3 = false;
                const unsigned int tag = (unsigned int)step;
                int guard = 0;
                for (;;) {
                    if (!k0) v0 = __hip_atomic_load(&src[0], __ATOMIC_RELAXED,
                                                    __HIP_MEMORY_SCOPE_AGENT);
                    if (!k1) v1 = __hip_atomic_load(&src[1], __ATOMIC_RELAXED,
                                                    __HIP_MEMORY_SCOPE_AGENT);
                    if (!k2) v2 = __hip_atomic_load(&src[2], __ATOMIC_RELAXED,
                                                    __HIP_MEMORY_SCOPE_AGENT);
                    if (!k3) v3 = __hip_atomic_load(&src[3], __ATOMIC_RELAXED,
                                                    __HIP_MEMORY_SCOPE_AGENT);
                    k0 = k0 || ((unsigned int)(v0 >> 32) == tag);
                    k1 = k1 || ((unsigned int)(v1 >> 32) == tag);
                    k2 = k2 || ((unsigned int)(v2 >> 32) == tag);
                    k3 = k3 || ((unsigned int)(v3 >> 32) == tag);
                    if (k0 & k1 & k2 & k3) break;
                    if (++guard > (1 << 20)) break;   // safety: never expected
                    __builtin_amdgcn_s_sleep(1);
                }
                h_lds[tid * 4 + 0] = __uint_as_float((unsigned int)v0);
                h_lds[tid * 4 + 1] = __uint_as_float((unsigned int)v1);
                h_lds[tid * 4 + 2] = __uint_as_float((unsigned int)v2);
                h_lds[tid * 4 + 3] = __uint_as_float((unsigned int)v3);
            }
            __syncthreads();
        }
    }
}

// ---------------------------------------------------------------- launch
extern "C" void kernel_launch(void* const* d_in, const int* in_sizes, int n_in,
                              void* d_out, int out_size, void* d_ws, size_t ws_size,
                              hipStream_t stream) {
    const int*   tokens = (const int*)d_in[0];
    const float* emb    = (const float*)d_in[1];
    const float* w_ih   = (const float*)d_in[2];
    const float* w_hh   = (const float*)d_in[3];
    const float* b_ih   = (const float*)d_in[4];
    const float* b_hh   = (const float*)d_in[5];
    float* out = (float*)d_out;

    char* ws = (char*)d_ws;
    unsigned long long* hbuf = (unsigned long long*)ws;              // 16 KB
    float* X  = (float*)(ws + (size_t)16384);                        // 16 MB
    float* gx = (float*)(ws + (size_t)16384 + (size_t)TT * HD * 4);  // 64 MB

    hipMemsetAsync(hbuf, 0, 2 * HD * sizeof(unsigned long long), stream);
    embed_kernel<<<TT, 256, 0, stream>>>(tokens, emb, X);
    gemm_gx<<<dim3(TT / BM, GD / BN), 256, 0, stream>>>(X, w_ih, b_ih, b_hh, gx);
    lstm_scan<<<NWG, 256, 0, stream>>>(gx, w_hh, out, hbuf);
}

// Round 2
// 15974.666 us; speedup vs baseline: 1.2407x; 1.2407x over previous
//
#include <hip/hip_runtime.h>
#include <hip/hip_bf16.h>

#define HD   1024
#define GD   4096   // 4*H
#define TT   4096
#define NWG  256

// ---------------------------------------------------------------- embed
__global__ void embed_kernel(const int* __restrict__ tokens,
                             const float* __restrict__ emb,
                             float* __restrict__ X) {
    int t = blockIdx.x;
    int tok = tokens[t];
    const float4* src = reinterpret_cast<const float4*>(emb + (size_t)tok * HD);
    float4* dst = reinterpret_cast<float4*>(X + (size_t)t * HD);
    dst[threadIdx.x] = src[threadIdx.x];
}

// ---------------------------------------------------------------- gx GEMM
// gx[t][n] = sum_k X[t][k] * Wih[n][k] + bih[n] + bhh[n]
#define BM 128
#define BN 128
#define BK 16
#define LDP 132

__global__ __launch_bounds__(256, 2) void gemm_gx(
    const float* __restrict__ X,      // TT x HD
    const float* __restrict__ Wih,    // GD x HD
    const float* __restrict__ bih,
    const float* __restrict__ bhh,
    float* __restrict__ gxout)        // TT x GD
{
    __shared__ float As[BK][LDP];
    __shared__ float Bs[BK][LDP];
    const int tid = threadIdx.x;
    const int m0 = blockIdx.x * BM;
    const int n0 = blockIdx.y * BN;
    const int tx = tid & 15;
    const int ty = tid >> 4;

    float acc[8][8] = {};

    for (int kt = 0; kt < HD; kt += BK) {
#pragma unroll
        for (int p = 0; p < 2; ++p) {
            int e = p * 256 + tid;           // 0..511 float4 slots
            int row = e >> 2;
            int quad = e & 3;
            float4 av = *reinterpret_cast<const float4*>(
                &X[(size_t)(m0 + row) * HD + kt + quad * 4]);
            float4 bv = *reinterpret_cast<const float4*>(
                &Wih[(size_t)(n0 + row) * HD + kt + quad * 4]);
            As[quad * 4 + 0][row] = av.x;
            As[quad * 4 + 1][row] = av.y;
            As[quad * 4 + 2][row] = av.z;
            As[quad * 4 + 3][row] = av.w;
            Bs[quad * 4 + 0][row] = bv.x;
            Bs[quad * 4 + 1][row] = bv.y;
            Bs[quad * 4 + 2][row] = bv.z;
            Bs[quad * 4 + 3][row] = bv.w;
        }
        __syncthreads();
#pragma unroll
        for (int k = 0; k < BK; ++k) {
            float4 a0 = *reinterpret_cast<const float4*>(&As[k][ty * 8]);
            float4 a1 = *reinterpret_cast<const float4*>(&As[k][ty * 8 + 4]);
            float4 b0 = *reinterpret_cast<const float4*>(&Bs[k][tx * 8]);
            float4 b1 = *reinterpret_cast<const float4*>(&Bs[k][tx * 8 + 4]);
            float a[8] = {a0.x, a0.y, a0.z, a0.w, a1.x, a1.y, a1.z, a1.w};
            float b[8] = {b0.x, b0.y, b0.z, b0.w, b1.x, b1.y, b1.z, b1.w};
#pragma unroll
            for (int i = 0; i < 8; ++i)
#pragma unroll
                for (int j = 0; j < 8; ++j)
                    acc[i][j] += a[i] * b[j];
        }
        __syncthreads();
    }

    float bias[8];
#pragma unroll
    for (int j = 0; j < 8; ++j) {
        int n = n0 + tx * 8 + j;
        bias[j] = bih[n] + bhh[n];
    }
#pragma unroll
    for (int i = 0; i < 8; ++i) {
        size_t o = (size_t)(m0 + ty * 8 + i) * GD + n0 + tx * 8;
        float4 s0 = {acc[i][0] + bias[0], acc[i][1] + bias[1],
                     acc[i][2] + bias[2], acc[i][3] + bias[3]};
        float4 s1 = {acc[i][4] + bias[4], acc[i][5] + bias[5],
                     acc[i][6] + bias[6], acc[i][7] + bias[7]};
        *reinterpret_cast<float4*>(&gxout[o]) = s0;
        *reinterpret_cast<float4*>(&gxout[o + 4]) = s1;
    }
}

// ---------------------------------------------------------------- LSTM scan
// 256 WGs x 256 threads (4 waves). Wave w of WG b owns h element j = b*4+w
// and computes ALL four gates for it: lane = gate*16 + chunk.
// Thread's weight columns are {chunk*4 + 64q + e} -> float4 LDS reads hit
// 32 banks 2-way (free). Gate math wave-uniform; c state wave-replicated.
// One __syncthreads per step (double-buffered h in LDS).
__device__ __forceinline__ float sigmoid_(float x) {
    return 1.f / (1.f + __expf(-x));
}
__device__ __forceinline__ float tanh_(float x) {
    return __builtin_fmaf(2.f, 1.f / (1.f + __expf(-2.f * x)), -1.f);
}

__global__ __launch_bounds__(256, 1) void lstm_scan(
    const float* __restrict__ gx,                 // TT x GD (includes biases)
    const float* __restrict__ whh,                // GD x HD
    float* __restrict__ out,                      // TT*HD + HD + HD
    unsigned long long* __restrict__ hbuf)        // 2 x HD
{
    const int tid   = threadIdx.x;
    const int b     = blockIdx.x;
    const int lane  = tid & 63;
    const int wv    = tid >> 6;          // wave id == jj
    const int chunk = lane & 15;         // col chunk
    const int gate  = lane >> 4;         // 0..3 (i,f,g,o)
    const int j     = b * 4 + wv;        // owned h element
    const int R     = gate * HD + j;     // weight row for this lane

    // weights -> registers (interleaved column layout)
    float w[64];
    {
        const float* wrow = whh + (size_t)R * HD;
#pragma unroll
        for (int q = 0; q < 16; ++q) {
            float4 v = *reinterpret_cast<const float4*>(&wrow[chunk * 4 + q * 64]);
            w[q * 4 + 0] = v.x; w[q * 4 + 1] = v.y;
            w[q * 4 + 2] = v.z; w[q * 4 + 3] = v.w;
        }
    }

    __shared__ float h_lds[2][HD];
#pragma unroll
    for (int q = 0; q < 4; ++q) h_lds[0][tid * 4 + q] = 0.f;   // h(0) = 0
    __syncthreads();

    float c_reg = 0.f;
    float gx_cur = gx[R];                // step 1 value (wave-group broadcast)

    for (int s = 1; s <= TT; ++s) {
        const int cb = (s - 1) & 1;      // buffer holding h(s-1)
        const int nb = s & 1;            // buffer for h(s)

        // prefetch next step's gx (consumed next iteration)
        float gx_nxt = 0.f;
        if (s < TT) gx_nxt = gx[(size_t)s * GD + R];

        // dot product over h(s-1): 64 FMA per lane, conflict-free LDS reads
        float acc = (chunk == 0) ? gx_cur : 0.f;
        {
            const float* hb = h_lds[cb];
#pragma unroll
            for (int q = 0; q < 16; ++q) {
                float4 hv = *reinterpret_cast<const float4*>(&hb[chunk * 4 + q * 64]);
                acc = __builtin_fmaf(w[q * 4 + 0], hv.x, acc);
                acc = __builtin_fmaf(w[q * 4 + 1], hv.y, acc);
                acc = __builtin_fmaf(w[q * 4 + 2], hv.z, acc);
                acc = __builtin_fmaf(w[q * 4 + 3], hv.w, acc);
            }
        }
        // reduce within each 16-lane gate group
        acc += __shfl_xor(acc, 1, 64);
        acc += __shfl_xor(acc, 2, 64);
        acc += __shfl_xor(acc, 4, 64);
        acc += __shfl_xor(acc, 8, 64);
        // broadcast the four gate sums to every lane of the wave
        float si = __shfl(acc, 0, 64);
        float sf = __shfl(acc, 16, 64);
        float sg = __shfl(acc, 32, 64);
        float so = __shfl(acc, 48, 64);

        // gate math, wave-uniform (replicated in all 64 lanes)
        float ii = sigmoid_(si);
        float ff = sigmoid_(sf);
        float gg = tanh_(sg);
        float oo = sigmoid_(so);
        c_reg = __builtin_fmaf(ff, c_reg, ii * gg);
        float hh = oo * tanh_(c_reg);

        if (lane == 0) {
            // publish first (critical path for all other WGs)
            unsigned long long pkt =
                ((unsigned long long)(unsigned)s << 32) | __float_as_uint(hh);
            __hip_atomic_store(&hbuf[(size_t)nb * HD + j], pkt,
                               __ATOMIC_RELAXED, __HIP_MEMORY_SCOPE_AGENT);
            h_lds[nb][j] = hh;                          // own value, LDS path
            out[(size_t)(s - 1) * HD + j] = hh;         // hs output
            if (s == TT) {
                out[(size_t)TT * HD + j] = hh;          // h_n
                out[(size_t)TT * HD + HD + j] = c_reg;  // c_n
            }
        }
        gx_cur = gx_nxt;

        // gather h(s) from other WGs: thread t owns WG t's 4 words
        if (s < TT) {
            if (tid != b) {
                unsigned long long* src = &hbuf[(size_t)nb * HD + tid * 4];
                unsigned long long v0 = 0, v1 = 0, v2 = 0, v3 = 0;
                bool k0 = false, k1 = false, k2 = false, k3 = false;
                const unsigned int tag = (unsigned int)s;
                int guard = 0;
                for (;;) {
                    if (!k0) v0 = __hip_atomic_load(&src[0], __ATOMIC_RELAXED,
                                                    __HIP_MEMORY_SCOPE_AGENT);
                    if (!k1) v1 = __hip_atomic_load(&src[1], __ATOMIC_RELAXED,
                                                    __HIP_MEMORY_SCOPE_AGENT);
                    if (!k2) v2 = __hip_atomic_load(&src[2], __ATOMIC_RELAXED,
                                                    __HIP_MEMORY_SCOPE_AGENT);
                    if (!k3) v3 = __hip_atomic_load(&src[3], __ATOMIC_RELAXED,
                                                    __HIP_MEMORY_SCOPE_AGENT);
                    k0 = k0 || ((unsigned int)(v0 >> 32) == tag);
                    k1 = k1 || ((unsigned int)(v1 >> 32) == tag);
                    k2 = k2 || ((unsigned int)(v2 >> 32) == tag);
                    k3 = k3 || ((unsigned int)(v3 >> 32) == tag);
                    if (k0 & k1 & k2 & k3) break;
                    if (++guard > (1 << 18)) break;   // safety: never expected
                    __builtin_amdgcn_s_sleep(1);
                }
                float4 hv;
                hv.x = __uint_as_float((unsigned int)v0);
                hv.y = __uint_as_float((unsigned int)v1);
                hv.z = __uint_as_float((unsigned int)v2);
                hv.w = __uint_as_float((unsigned int)v3);
                *reinterpret_cast<float4*>(&h_lds[nb][tid * 4]) = hv;
            }
            __syncthreads();
        }
    }
}

// ---------------------------------------------------------------- launch
extern "C" void kernel_launch(void* const* d_in, const int* in_sizes, int n_in,
                              void* d_out, int out_size, void* d_ws, size_t ws_size,
                              hipStream_t stream) {
    const int*   tokens = (const int*)d_in[0];
    const float* emb    = (const float*)d_in[1];
    const float* w_ih   = (const float*)d_in[2];
    const float* w_hh   = (const float*)d_in[3];
    const float* b_ih   = (const float*)d_in[4];
    const float* b_hh   = (const float*)d_in[5];
    float* out = (float*)d_out;

    char* ws = (char*)d_ws;
    unsigned long long* hbuf = (unsigned long long*)ws;              // 16 KB
    float* X  = (float*)(ws + (size_t)16384);                        // 16 MB
    float* gx = (float*)(ws + (size_t)16384 + (size_t)TT * HD * 4);  // 64 MB

    hipMemsetAsync(hbuf, 0, 2 * HD * sizeof(unsigned long long), stream);
    embed_kernel<<<TT, 256, 0, stream>>>(tokens, emb, X);
    gemm_gx<<<dim3(TT / BM, GD / BN), 256, 0, stream>>>(X, w_ih, b_ih, b_hh, gx);
    lstm_scan<<<NWG, 256, 0, stream>>>(gx, w_hh, out, hbuf);
}